// Round 4
// baseline (345.853 us; speedup 1.0000x reference)
//
#include <hip/hip_runtime.h>

// Round 4: wave-chunked output-centric unpool — the H_A/H_B discriminator.
//
// r3 showed store cache-policy is irrelevant (335.3 vs 336.3). Remaining
// hypotheses: H_A = kernel ~130us capped by structure (launch churn, per-wave
// MLP=1, loader/writer role imbalance); H_B = kernel already ~61us at the
// 384MB/6.3TB/s roofline and ~275us is harness reset overhead.
//
// This kernel removes every H_A candidate at once, without r2's 64MiB-stride
// mistake:
//   - each WAVE owns 512 consecutive quads (8 full (oh,ow) pixels, 8KB out),
//     one thread handles 8 quads at 1KiB wave-stride: waves 262k -> 32k,
//     8 independent stores (and 8 loads) in flight per wave;
//   - a wave's 8 pixels share oh and span ow0..ow0+7 with ow0 % 8 == 0, so
//     roles are compile-time: odd oh -> 8 pure zero-stores; even oh ->
//     iterations 0,2,4,6 are canonical loaders (w = w0+k, input reads are 4KB
//     contiguous per stream), 1,3,5,7 are zero-stores. Loads all issue first.
// Semantics unchanged: canonical idx -> store v; else zero + atomicAdd
// (reference duplicate-sum fallback).
//
// Geometry: H=W=256, C=256, OH=OW=512. NQ = 16,777,216 output quads.
// threads = NQ/8 = 2,097,152; grid = 8192 blocks of 256.

typedef float  f32x4 __attribute__((ext_vector_type(4)));
typedef int    i32x4 __attribute__((ext_vector_type(4)));

__global__ __launch_bounds__(256) void unpool_wc8_kernel(
    const float* __restrict__ val,
    const int*   __restrict__ idx,
    float*       __restrict__ out)
{
    const int t    = blockIdx.x * blockDim.x + threadIdx.x;  // [0, NQ/8)
    const int lane = t & 63;
    const int wid  = t >> 6;        // wave id, [0, 32768)

    const int baseq = wid << 9;     // first quad of this wave's 512-quad chunk
    const int pix0  = wid << 3;     // first of 8 consecutive pixels (ow0%8==0)
    const int oh    = pix0 >> 9;    // output row, shared by all 8 pixels

    f32x4* o = reinterpret_cast<f32x4*>(out);
    const f32x4 z = (f32x4)(0.f);

    if (oh & 1) {
        // Odd output row: pure streamer wave, 8 independent 1KiB stores (8KB).
        #pragma unroll
        for (int i = 0; i < 8; ++i)
            o[baseq + i * 64 + lane] = z;
        return;
    }

    // Even row: pixels at i=0,2,4,6 have even ow (canonical targets of pooled
    // (h, w0+k)); i=1,3,5,7 have odd ow (zeros).
    const int h    = oh >> 1;
    const int w0   = (pix0 & 511) >> 1;
    const int qin0 = (h << 14) + (w0 << 6) + lane;  // input quad, 4KB/stream

    const f32x4* vq = reinterpret_cast<const f32x4*>(val);
    const i32x4* iq = reinterpret_cast<const i32x4*>(idx);

    // Issue all 8 loads up front (deep MLP, no dependent op between them).
    f32x4 v[4]; i32x4 id[4];
    #pragma unroll
    for (int k = 0; k < 4; ++k) {
        v[k]  = __builtin_nontemporal_load(vq + qin0 + k * 64);
        id[k] = __builtin_nontemporal_load(iq + qin0 + k * 64);
    }

    // Zero stores for the odd-ow pixels — independent of the loads.
    #pragma unroll
    for (int k = 0; k < 4; ++k)
        o[baseq + (2 * k + 1) * 64 + lane] = z;

    // Canonical-check + store for the even-ow pixels.
    #pragma unroll
    for (int k = 0; k < 4; ++k) {
        const int q = baseq + 2 * k * 64 + lane;
        const int p = q << 2;  // expected canonical flat float index (< 2^26)
        if (__builtin_expect(id[k].x == p     && id[k].y == p + 1 &&
                             id[k].z == p + 2 && id[k].w == p + 3, 1)) {
            o[q] = v[k];       // canonical fast path
        } else {
            o[q] = z;          // zero the quad, scatter per reference
            atomicAdd(out + id[k].x, v[k].x);
            atomicAdd(out + id[k].y, v[k].y);
            atomicAdd(out + id[k].z, v[k].z);
            atomicAdd(out + id[k].w, v[k].w);
        }
    }
}

extern "C" void kernel_launch(void* const* d_in, const int* in_sizes, int n_in,
                              void* d_out, int out_size, void* d_ws, size_t ws_size,
                              hipStream_t stream) {
    const float* val = (const float*)d_in[0];
    const int*   idx = (const int*)d_in[1];
    float* out = (float*)d_out;

    const int n       = in_sizes[0];  // 16,777,216 pooled elements = NQ quads
    const int threads = n / 8;        // 8 quads per thread
    const int block   = 256;
    const int grid    = threads / block;  // 8192 blocks
    unpool_wc8_kernel<<<grid, block, 0, stream>>>(val, idx, out);
}